// Round 10
// baseline (912.255 us; speedup 1.0000x reference)
//
#include <hip/hip_runtime.h>
#include <hip/hip_bf16.h>
#include <cmath>

#define TT 512
#define BB 32
#define EE 256
#define HH 128
#define KCRF 12
#define NEGF (-10000.0f)

// ---------------------------------------------------------------------------
// K1: XG[row=t*32+b][col 0..1023] = embed[sent[b,t]] . W_cat[col]^T + bias
// Rewritten: 128x128 block tile, 8x8 micro-tile, float4 k-vectorized LDS
// reads (16 b128 reads per 256 FMA -- 4x fewer LDS instrs, 2x fewer LDS
// bytes/FMA than the old 4x8 tile). Interleaved row mapping (ty+16i, tx+16j)
// gives lane-stride = 1 row = 37 floats => bank stride 5 (gcd(5,32)=1),
// conflict-free b128 reads. Pad 37 chosen for exactly this.
// LDS 37.9KB, 1024 blocks, 256 threads.
// ---------------------------------------------------------------------------
__global__ __launch_bounds__(256) void k1_xg(const int* __restrict__ sent,
    const float* __restrict__ embed,
    const float* __restrict__ Wf, const float* __restrict__ bf,
    const float* __restrict__ Wr, const float* __restrict__ br,
    float* __restrict__ XG)
{
  __shared__ __align__(16) float As[128][37];
  __shared__ __align__(16) float Bs[128][37];
  const int tid = threadIdx.x;
  const int m0 = (blockIdx.x >> 3) * 128;
  const int n0 = (blockIdx.x & 7) * 128;
  const int ty = tid >> 4, tx = tid & 15;
  float acc[8][8];
#pragma unroll
  for (int i = 0; i < 8; ++i)
#pragma unroll
    for (int j = 0; j < 8; ++j) acc[i][j] = 0.f;

  for (int k0 = 0; k0 < 256; k0 += 32) {
#pragma unroll
    for (int r = 0; r < 4; ++r) {         // A: 128 rows x 32 k, gathered
      int idx = tid + r * 256;            // 0..1023
      int row = idx >> 3;                 // 0..127
      int c4 = (idx & 7) << 2;            // 0,4,..,28
      int R = m0 + row;
      int t = R >> 5, b = R & 31;
      *(float4*)&As[row][c4] =
          *(const float4*)(embed + (long)sent[b * TT + t] * 256 + k0 + c4);
    }
#pragma unroll
    for (int r = 0; r < 4; ++r) {         // B: 128 cols x 32 k of W_cat
      int idx = tid + r * 256;
      int row = idx >> 3;
      int c4 = (idx & 7) << 2;
      int col = n0 + row;
      const float* src = (col < 512) ? (Wf + (long)col * 256)
                                     : (Wr + (long)(col - 512) * 256);
      *(float4*)&Bs[row][c4] = *(const float4*)(src + k0 + c4);
    }
    __syncthreads();
#pragma unroll
    for (int k4i = 0; k4i < 8; ++k4i) {
      float4 a4[8], b4[8];
#pragma unroll
      for (int i = 0; i < 8; ++i) a4[i] = *(const float4*)&As[ty + 16 * i][k4i * 4];
#pragma unroll
      for (int j = 0; j < 8; ++j) b4[j] = *(const float4*)&Bs[tx + 16 * j][k4i * 4];
#pragma unroll
      for (int i = 0; i < 8; ++i)
#pragma unroll
        for (int j = 0; j < 8; ++j) {
          acc[i][j] = fmaf(a4[i].x, b4[j].x, acc[i][j]);
          acc[i][j] = fmaf(a4[i].y, b4[j].y, acc[i][j]);
          acc[i][j] = fmaf(a4[i].z, b4[j].z, acc[i][j]);
          acc[i][j] = fmaf(a4[i].w, b4[j].w, acc[i][j]);
        }
    }
    __syncthreads();
  }
#pragma unroll
  for (int i = 0; i < 8; ++i) {
    const long R = m0 + ty + 16 * i;
#pragma unroll
    for (int j = 0; j < 8; ++j) {
      const int col = n0 + tx + 16 * j;
      const float bias = (col < 512) ? bf[col] : br[col - 512];
      XG[R * 1024 + col] = acc[i][j] + bias;
    }
  }
}

// ---------------------------------------------------------------------------
// K2: LSTM scans -- UNCHANGED (round-3 anchor: 471us, VGPR 80 / SGPR 48,
// zero bank conflicts). Floor of the LDS-broadcast design family: per
// chain-step LDS must deliver 512 x 128 x 4B = 256KB on one CU (~2048cy).
// MFMA escape rejected: batch N=32/dir collapses work to 2-4 CUs. Do not
// touch.
// ---------------------------------------------------------------------------
__global__ __launch_bounds__(512) __attribute__((amdgpu_waves_per_eu(1)))
void k2_scan(const float* __restrict__ XG,
    const float* __restrict__ Whf, const float* __restrict__ Whr,
    const float* __restrict__ h0, const float* __restrict__ c0,
    float* __restrict__ HS)
{
  const int wg = blockIdx.x;
  const int dir = wg >> 5;
  const int b = wg & 31;
  const int j = threadIdx.x;
  const float* Wh = dir ? Whr : Whf;

  float4 w[32];
#pragma unroll
  for (int i = 0; i < 32; ++i)
    w[i] = *(const float4*)(Wh + (long)j * 128 + i * 4);

  __shared__ __align__(16) float hs[128];
  __shared__ float gs[512];
  float c = 0.f;
  if (j < 128) {
    hs[j] = h0[(dir * 32 + b) * 128 + j];
    c = c0[(dir * 32 + b) * 128 + j];
  }
  __syncthreads();

  const int t0 = dir ? (TT - 1) : 0;
  const long stepoff = dir ? -32768 : 32768;   // 32*1024 floats per t
  const float* xp = XG + ((long)t0 * 32 + b) * 1024 + dir * 512 + j;
  float xg_cur = *xp;
  const int gate = j >> 7;   // 0=i 1=f 2=g 3=o

  for (int s = 0; s < TT; ++s) {
    const int t = dir ? (TT - 1 - s) : s;
    float xg_nxt = 0.f;
    if (s + 1 < TT) { xp += stepoff; xg_nxt = *xp; }

    float a0 = xg_cur, a1 = 0.f, a2 = 0.f, a3 = 0.f;
#pragma unroll
    for (int i = 0; i < 32; ++i) {
      const float4 hv = *(const float4*)(hs + 4 * i);   // uniform -> broadcast
      a0 = fmaf(w[i].x, hv.x, a0);
      a1 = fmaf(w[i].y, hv.y, a1);
      a2 = fmaf(w[i].z, hv.z, a2);
      a3 = fmaf(w[i].w, hv.w, a3);
    }
    const float acc = (a0 + a1) + (a2 + a3);
    const float act = (gate == 2) ? tanhf(acc) : (1.f / (1.f + expf(-acc)));
    gs[j] = act;
    __syncthreads();           // gs ready; all reads of hs complete
    if (j < 128) {
      float ig = gs[j], fg = gs[128 + j], gg = gs[256 + j], og = gs[384 + j];
      c = fmaf(fg, c, ig * gg);
      float h = og * tanhf(c);
      hs[j] = h;
      HS[((long)t * 32 + b) * 256 + dir * 128 + j] = h;
    }
    __syncthreads();           // hs ready for next step
    xg_cur = xg_nxt;
  }
}

// ---------------------------------------------------------------------------
// K3: feats. FE layout [t][k][b]. (unchanged)
// ---------------------------------------------------------------------------
__global__ __launch_bounds__(64) void k3_feats(const float* __restrict__ HS,
    const float* __restrict__ Wout, const float* __restrict__ bout,
    float* __restrict__ FE)
{
  __shared__ __align__(16) float ws[12 * 256];
  __shared__ float bs[12];
  const int tid = threadIdx.x;
  for (int i = tid; i < 768; i += 64)
    ((float4*)ws)[i] = ((const float4*)Wout)[i];
  if (tid < 12) bs[tid] = bout[tid];
  __syncthreads();
  const long row = (long)blockIdx.x * 64 + tid;
  const float4* hp = (const float4*)(HS + row * 256);
  float acc[12];
#pragma unroll
  for (int k = 0; k < 12; ++k) acc[k] = bs[k];
  for (int e4 = 0; e4 < 64; ++e4) {
    float4 hv = hp[e4];
#pragma unroll
    for (int k = 0; k < 12; ++k) {
      const float4 wv = *(const float4*)&ws[k * 256 + e4 * 4];
      acc[k] = fmaf(hv.x, wv.x, acc[k]);
      acc[k] = fmaf(hv.y, wv.y, acc[k]);
      acc[k] = fmaf(hv.z, wv.z, acc[k]);
      acc[k] = fmaf(hv.w, wv.w, acc[k]);
    }
  }
  const int t = (int)(row >> 5), b = (int)(row & 31);
#pragma unroll
  for (int k = 0; k < 12; ++k) FE[((long)t * 12 + k) * 32 + b] = acc[k];
}

// ---------------------------------------------------------------------------
// K4: Viterbi -- REVERTED to the round-3 nibble-packed version (measured
// best: R3 rest-of-pipeline 338us vs R9's 367us with everything else
// bit-identical; the 1-wave-per-WG shfl variant exposed its serial chain).
// Double-buffered scores (1 barrier/step), nibble-packed pointers in LDS
// for the backtrace.
// ---------------------------------------------------------------------------
__global__ __launch_bounds__(384) void k4_viterbi(const float* __restrict__ FE,
    const float* __restrict__ trans, int* __restrict__ out)
{
  __shared__ unsigned char nib[TT * 192];   // 98304 B
  __shared__ float sc[2][32][12];
  __shared__ float tr[144];
  __shared__ unsigned char stag[2][384];
  __shared__ int btag[32];
  const int tid = threadIdx.x;
  const int b = tid & 31, nxt = tid >> 5;
  if (tid < 144) tr[tid] = trans[tid];
  if (nxt == 0) {
#pragma unroll
    for (int p = 0; p < 12; ++p) sc[0][b][p] = (p == 9) ? 0.f : NEGF;  // START=9
  }
  __syncthreads();
  float fnext = FE[nxt * 32 + b];
  for (int t = 0; t < TT; ++t) {
    const int cur = t & 1;
    const float feat = fnext;
    if (t + 1 < TT) fnext = FE[(t + 1) * 384 + nxt * 32 + b];
    float best = -1e30f; int arg = 0;
#pragma unroll
    for (int p = 0; p < 12; ++p) {
      float v = sc[cur][b][p] + tr[nxt * 12 + p];
      if (v > best) { best = v; arg = p; }
    }
    sc[cur ^ 1][b][nxt] = best + feat;
    stag[cur][b * 12 + nxt] = (unsigned char)arg;
    if (t > 0 && tid < 192) {
      const int bb = tid / 6, p = tid % 6;
      nib[(t - 1) * 192 + tid] =
          (unsigned char)(stag[cur ^ 1][bb * 12 + 2 * p] |
                          (stag[cur ^ 1][bb * 12 + 2 * p + 1] << 4));
    }
    __syncthreads();
  }
  if (tid < 192) {
    const int bb = tid / 6, p = tid % 6;
    nib[511 * 192 + tid] =
        (unsigned char)(stag[1][bb * 12 + 2 * p] | (stag[1][bb * 12 + 2 * p + 1] << 4));
  }
  if (nxt == 0) {
    float best = -1e30f; int arg = 0;
#pragma unroll
    for (int p = 0; p < 12; ++p) {
      float v = sc[0][b][p] + tr[10 * 12 + p];   // STOP=10
      if (v > best) { best = v; arg = p; }
    }
    btag[b] = arg;
  }
  __syncthreads();
  if (tid < 32) {
    int tag = btag[b];
    for (int t = TT - 1; t >= 0; --t) {
      out[b * TT + t] = tag;
      if (t) {
        unsigned char v = nib[t * 192 + b * 6 + (tag >> 1)];
        tag = (tag & 1) ? (v >> 4) : (v & 15);
      }
    }
  }
}

// ---------------------------------------------------------------------------
extern "C" void kernel_launch(void* const* d_in, const int* in_sizes, int n_in,
                              void* d_out, int out_size, void* d_ws, size_t ws_size,
                              hipStream_t stream)
{
  const int* sent = (const int*)d_in[0];
  const float* h0 = (const float*)d_in[1];
  const float* c0 = (const float*)d_in[2];
  const float* embed = (const float*)d_in[3];
  const float* Wif = (const float*)d_in[4];
  const float* Whf = (const float*)d_in[5];
  const float* bf = (const float*)d_in[6];
  const float* Wir = (const float*)d_in[7];
  const float* Whr = (const float*)d_in[8];
  const float* br = (const float*)d_in[9];
  const float* Wout = (const float*)d_in[10];
  const float* bout = (const float*)d_in[11];
  const float* trans = (const float*)d_in[12];

  char* ws = (char*)d_ws;
  float* XG = (float*)ws;                                   // 67,108,864 B
  float* HS = (float*)(ws + 67108864);                      // 16,777,216 B
  float* FE = (float*)(ws + 67108864 + 16777216);           //    786,432 B
  int* out = (int*)d_out;

  hipLaunchKernelGGL(k1_xg, dim3(1024), dim3(256), 0, stream,
                     sent, embed, Wif, bf, Wir, br, XG);
  hipLaunchKernelGGL(k2_scan, dim3(64), dim3(512), 0, stream,
                     XG, Whf, Whr, h0, c0, HS);
  hipLaunchKernelGGL(k3_feats, dim3(256), dim3(64), 0, stream,
                     HS, Wout, bout, FE);
  hipLaunchKernelGGL(k4_viterbi, dim3(1), dim3(384), 0, stream,
                     FE, trans, out);
}

// Round 11
// 780.361 us; speedup vs baseline: 1.1690x; 1.1690x over previous
//
#include <hip/hip_runtime.h>
#include <hip/hip_bf16.h>
#include <cmath>

#define TT 512
#define BB 32
#define EE 256
#define HH 128
#define KCRF 12
#define NEGF (-10000.0f)

// ---------------------------------------------------------------------------
// K1: XG[row=t*32+b][col 0..1023] = embed[sent[b,t]] . W_cat[col]^T + bias
// REVERTED to the round-1..9 proven version (4x8 micro, 64x128 tile, 2048
// blocks). The R10 8x8 rewrite regressed rest-of-pipeline 338->441us
// (register pressure killed latency hiding). Do not touch again without
// per-kernel profiling.
// ---------------------------------------------------------------------------
__global__ __launch_bounds__(256) void k1_xg(const int* __restrict__ sent,
    const float* __restrict__ embed,
    const float* __restrict__ Wf, const float* __restrict__ bf,
    const float* __restrict__ Wr, const float* __restrict__ br,
    float* __restrict__ XG)
{
  __shared__ __align__(16) float As[64][36];
  __shared__ __align__(16) float Bs[128][36];
  const int tid = threadIdx.x;
  const int m0 = (blockIdx.x >> 3) * 64;
  const int n0 = (blockIdx.x & 7) * 128;
  const int ty = tid >> 4, tx = tid & 15;
  float acc[4][8];
#pragma unroll
  for (int i = 0; i < 4; ++i)
#pragma unroll
    for (int j = 0; j < 8; ++j) acc[i][j] = 0.f;

  for (int k0 = 0; k0 < 256; k0 += 32) {
#pragma unroll
    for (int r = 0; r < 2; ++r) {
      int idx = tid + r * 256;
      int row = idx >> 3;
      int c4 = (idx & 7) << 2;
      int R = m0 + row;
      int t = R >> 5, b = R & 31;
      const float4 v = *(const float4*)(embed + (long)sent[b * TT + t] * 256 + k0 + c4);
      *(float4*)&As[row][c4] = v;
    }
#pragma unroll
    for (int r = 0; r < 4; ++r) {
      int idx = tid + r * 256;
      int row = idx >> 3;
      int c4 = (idx & 7) << 2;
      int col = n0 + row;
      const float* src = (col < 512) ? (Wf + (long)col * 256) : (Wr + (long)(col - 512) * 256);
      const float4 v = *(const float4*)(src + k0 + c4);
      *(float4*)&Bs[row][c4] = v;
    }
    __syncthreads();
#pragma unroll
    for (int kk = 0; kk < 32; ++kk) {
      float a[4], bv[8];
#pragma unroll
      for (int i = 0; i < 4; ++i) a[i] = As[ty * 4 + i][kk];
#pragma unroll
      for (int j = 0; j < 8; ++j) bv[j] = Bs[tx + 16 * j][kk];
#pragma unroll
      for (int i = 0; i < 4; ++i)
#pragma unroll
        for (int j = 0; j < 8; ++j) acc[i][j] = fmaf(a[i], bv[j], acc[i][j]);
    }
    __syncthreads();
  }
#pragma unroll
  for (int i = 0; i < 4; ++i) {
    int R = m0 + ty * 4 + i;
#pragma unroll
    for (int j = 0; j < 8; ++j) {
      int col = n0 + tx + 16 * j;
      float bias = (col < 512) ? bf[col] : br[col - 512];
      XG[(long)R * 1024 + col] = acc[i][j] + bias;
    }
  }
}

// ---------------------------------------------------------------------------
// K2: LSTM scans -- UNCHANGED anchor (471us, VGPR 80 / SGPR 48, zero bank
// conflicts, reproduced 3x). Floor of the LDS-broadcast design family.
// Do not touch.
// ---------------------------------------------------------------------------
__global__ __launch_bounds__(512) __attribute__((amdgpu_waves_per_eu(1)))
void k2_scan(const float* __restrict__ XG,
    const float* __restrict__ Whf, const float* __restrict__ Whr,
    const float* __restrict__ h0, const float* __restrict__ c0,
    float* __restrict__ HS)
{
  const int wg = blockIdx.x;
  const int dir = wg >> 5;
  const int b = wg & 31;
  const int j = threadIdx.x;
  const float* Wh = dir ? Whr : Whf;

  float4 w[32];
#pragma unroll
  for (int i = 0; i < 32; ++i)
    w[i] = *(const float4*)(Wh + (long)j * 128 + i * 4);

  __shared__ __align__(16) float hs[128];
  __shared__ float gs[512];
  float c = 0.f;
  if (j < 128) {
    hs[j] = h0[(dir * 32 + b) * 128 + j];
    c = c0[(dir * 32 + b) * 128 + j];
  }
  __syncthreads();

  const int t0 = dir ? (TT - 1) : 0;
  const long stepoff = dir ? -32768 : 32768;   // 32*1024 floats per t
  const float* xp = XG + ((long)t0 * 32 + b) * 1024 + dir * 512 + j;
  float xg_cur = *xp;
  const int gate = j >> 7;   // 0=i 1=f 2=g 3=o

  for (int s = 0; s < TT; ++s) {
    const int t = dir ? (TT - 1 - s) : s;
    float xg_nxt = 0.f;
    if (s + 1 < TT) { xp += stepoff; xg_nxt = *xp; }

    float a0 = xg_cur, a1 = 0.f, a2 = 0.f, a3 = 0.f;
#pragma unroll
    for (int i = 0; i < 32; ++i) {
      const float4 hv = *(const float4*)(hs + 4 * i);   // uniform -> broadcast
      a0 = fmaf(w[i].x, hv.x, a0);
      a1 = fmaf(w[i].y, hv.y, a1);
      a2 = fmaf(w[i].z, hv.z, a2);
      a3 = fmaf(w[i].w, hv.w, a3);
    }
    const float acc = (a0 + a1) + (a2 + a3);
    const float act = (gate == 2) ? tanhf(acc) : (1.f / (1.f + expf(-acc)));
    gs[j] = act;
    __syncthreads();           // gs ready; all reads of hs complete
    if (j < 128) {
      float ig = gs[j], fg = gs[128 + j], gg = gs[256 + j], og = gs[384 + j];
      c = fmaf(fg, c, ig * gg);
      float h = og * tanhf(c);
      hs[j] = h;
      HS[((long)t * 32 + b) * 256 + dir * 128 + j] = h;
    }
    __syncthreads();           // hs ready for next step
    xg_cur = xg_nxt;
  }
}

// ---------------------------------------------------------------------------
// K3: feats. FE layout [t][k][b]. (unchanged)
// ---------------------------------------------------------------------------
__global__ __launch_bounds__(64) void k3_feats(const float* __restrict__ HS,
    const float* __restrict__ Wout, const float* __restrict__ bout,
    float* __restrict__ FE)
{
  __shared__ __align__(16) float ws[12 * 256];
  __shared__ float bs[12];
  const int tid = threadIdx.x;
  for (int i = tid; i < 768; i += 64)
    ((float4*)ws)[i] = ((const float4*)Wout)[i];
  if (tid < 12) bs[tid] = bout[tid];
  __syncthreads();
  const long row = (long)blockIdx.x * 64 + tid;
  const float4* hp = (const float4*)(HS + row * 256);
  float acc[12];
#pragma unroll
  for (int k = 0; k < 12; ++k) acc[k] = bs[k];
  for (int e4 = 0; e4 < 64; ++e4) {
    float4 hv = hp[e4];
#pragma unroll
    for (int k = 0; k < 12; ++k) {
      const float4 wv = *(const float4*)&ws[k * 256 + e4 * 4];
      acc[k] = fmaf(hv.x, wv.x, acc[k]);
      acc[k] = fmaf(hv.y, wv.y, acc[k]);
      acc[k] = fmaf(hv.z, wv.z, acc[k]);
      acc[k] = fmaf(hv.w, wv.w, acc[k]);
    }
  }
  const int t = (int)(row >> 5), b = (int)(row & 31);
#pragma unroll
  for (int k = 0; k < 12; ++k) FE[((long)t * 12 + k) * 32 + b] = acc[k];
}

// ---------------------------------------------------------------------------
// K4: Viterbi, single-wave WGs. 8 WGs x 64 threads; WG handles 4 batches
// (b = blockIdx*4 + bsub); lane = bsub*12 + nxt (48 active). Scores in a
// tiny sc[2][4][12] LDS table, read as 3 aligned ds_read_b128 (4 distinct
// addrs -> conflict-free); 12-way max chain is pure VALU; ONE single-wave
// barrier per step (near-free). Exactly one LDS round-trip latency exposed
// per step -- vs R3's 6-wave barrier + 12 per-lane b32 reads, and vs R9's
// 12 SERIAL shfl ops (the proven-bad variant). Pointers as bytes in per-WG
// LDS (24KB); backtrace parallel across the 8 WGs/CUs.
// Strict > ascending p == jnp.argmax first-max semantics.
// ---------------------------------------------------------------------------
__global__ __launch_bounds__(64) void k4_viterbi(const float* __restrict__ FE,
    const float* __restrict__ trans, int* __restrict__ out)
{
  __shared__ unsigned char ptrl[TT * 48];       // [t][bsub][12]  24576 B
  __shared__ __align__(16) float sc[2][4][12];  // double-buffered scores
  const int l = threadIdx.x;
  const int bsub = l / 12;                      // 0..5; active if <4
  const int nxt = l % 12;
  const bool act = (bsub < 4);
  const int bs = act ? bsub : 0;                // clamped for reads
  const int b = blockIdx.x * 4 + bs;

  float tr[12], stopv[12];
#pragma unroll
  for (int p = 0; p < 12; ++p) tr[p] = trans[nxt * 12 + p];
#pragma unroll
  for (int p = 0; p < 12; ++p) stopv[p] = trans[10 * 12 + p];   // STOP=10

  if (act) sc[0][bsub][nxt] = (nxt == 9) ? 0.f : NEGF;          // START=9
  __syncthreads();

  float fnext = FE[nxt * 32 + b];
  for (int t = 0; t < TT; ++t) {
    const int cur = t & 1;
    const float feat = fnext;
    if (t + 1 < TT) fnext = FE[((t + 1) * 12 + nxt) * 32 + b];

    float sp[12];
    *(float4*)&sp[0] = *(const float4*)&sc[cur][bs][0];
    *(float4*)&sp[4] = *(const float4*)&sc[cur][bs][4];
    *(float4*)&sp[8] = *(const float4*)&sc[cur][bs][8];
    float best = -1e30f; int arg = 0;
#pragma unroll
    for (int p = 0; p < 12; ++p) {
      const float v = sp[p] + tr[p];
      if (v > best) { best = v; arg = p; }
    }
    if (act) {
      sc[cur ^ 1][bsub][nxt] = best + feat;     // write other buffer: no WAR
      ptrl[t * 48 + bsub * 12 + nxt] = (unsigned char)arg;
    }
    __syncthreads();                            // single wave: near-free
    }

  // final scores are in sc[0] after 512 toggles
  float best = -1e30f; int arg = 0;
#pragma unroll
  for (int p = 0; p < 12; ++p) {
    const float v = sc[0][bs][p] + stopv[p];
    if (v > best) { best = v; arg = p; }
  }
  if (act && nxt == 0) {
    int tag = arg;
    for (int t = TT - 1; t >= 0; --t) {
      out[b * TT + t] = tag;
      if (t) tag = ptrl[t * 48 + bsub * 12 + tag];
    }
  }
}

// ---------------------------------------------------------------------------
extern "C" void kernel_launch(void* const* d_in, const int* in_sizes, int n_in,
                              void* d_out, int out_size, void* d_ws, size_t ws_size,
                              hipStream_t stream)
{
  const int* sent = (const int*)d_in[0];
  const float* h0 = (const float*)d_in[1];
  const float* c0 = (const float*)d_in[2];
  const float* embed = (const float*)d_in[3];
  const float* Wif = (const float*)d_in[4];
  const float* Whf = (const float*)d_in[5];
  const float* bf = (const float*)d_in[6];
  const float* Wir = (const float*)d_in[7];
  const float* Whr = (const float*)d_in[8];
  const float* br = (const float*)d_in[9];
  const float* Wout = (const float*)d_in[10];
  const float* bout = (const float*)d_in[11];
  const float* trans = (const float*)d_in[12];

  char* ws = (char*)d_ws;
  float* XG = (float*)ws;                                   // 67,108,864 B
  float* HS = (float*)(ws + 67108864);                      // 16,777,216 B
  float* FE = (float*)(ws + 67108864 + 16777216);           //    786,432 B
  int* out = (int*)d_out;

  hipLaunchKernelGGL(k1_xg, dim3(2048), dim3(256), 0, stream,
                     sent, embed, Wif, bf, Wir, br, XG);
  hipLaunchKernelGGL(k2_scan, dim3(64), dim3(512), 0, stream,
                     XG, Whf, Whr, h0, c0, HS);
  hipLaunchKernelGGL(k3_feats, dim3(256), dim3(64), 0, stream,
                     HS, Wout, bout, FE);
  hipLaunchKernelGGL(k4_viterbi, dim3(8), dim3(64), 0, stream,
                     FE, trans, out);
}